// Round 7
// baseline (145.796 us; speedup 1.0000x reference)
//
#include <hip/hip_runtime.h>

typedef unsigned int   u32;
typedef unsigned short u16;
typedef short bf16x8 __attribute__((ext_vector_type(8)));
typedef float f32x4  __attribute__((ext_vector_type(4)));
typedef float f32x2  __attribute__((ext_vector_type(2)));

#define CIN   128
#define COUT  128
#define Hh    64
#define Ww    64
#define Bb    8
#define NKPOS 9
#define NCHUNK 36                 // K = 1152 = 36 x 32
#define XT_ELEMS (Bb*Hh*Ww*CIN)   // 4,194,304 u16 (8 MB)
#define WT_ELEMS (NCHUNK*8*64*8)  // 147,456 u16 (288 KB)
// V layout: [b][cg(8)][kpos(9)][pos(4096)][c16(16)] u16  -> k = kpos*128+cg*16+c
#define V_ELEMS ((size_t)Bb*8*9*4096*16)   // 37.75M u16 (75.5 MB)

// ---- helpers ----------------------------------------------------------
__device__ __forceinline__ float bflo(u32 u){ return __uint_as_float(u << 16); }
__device__ __forceinline__ float bfhi(u32 u){ return __uint_as_float(u & 0xffff0000u); }

__device__ __forceinline__ u32 pack2(float a, float b){
    u32 lo = __float_as_uint(a) + 0x8000u;
    u32 hi = __float_as_uint(b) + 0x8000u;
    return __builtin_amdgcn_perm(hi, lo, 0x07060302u);
}
__device__ __forceinline__ u16 tobf(float a){
    u32 ua = __float_as_uint(a);
    ua += 0x7fffu + ((ua >> 16) & 1u);
    return (u16)(ua >> 16);
}

// ---- kernel 1: x [B,CIN,H,W] f32 -> xT [B,H,W,CIN] bf16 ---------------
__global__ __launch_bounds__(256) void k_transpose(const float* __restrict__ x,
                                                   u16* __restrict__ xT){
    __shared__ float lds[64*132];
    int bi = blockIdx.x;
    int hb = bi & 63, b = bi >> 6;
    int tid = threadIdx.x;

    {   int r = tid >> 1, cq = tid & 1;
        const float* xp = x + ((size_t)(b*128 + r))*4096 + hb*64 + cq*32;
        float4 v[8];
#pragma unroll
        for (int k = 0; k < 8; ++k) v[k] = *(const float4*)(xp + k*4);
        float* dst = lds + (cq*32)*132 + r;
#pragma unroll
        for (int k = 0; k < 8; ++k){
            dst[(k*4+0)*132] = v[k].x;
            dst[(k*4+1)*132] = v[k].y;
            dst[(k*4+2)*132] = v[k].z;
            dst[(k*4+3)*132] = v[k].w;
        }
    }
    __syncthreads();
    {   int s = tid >> 2, kq = tid & 3;
        const float* src = lds + s*132 + kq*32;
        u32 r16[16];
#pragma unroll
        for (int k = 0; k < 8; ++k){
            float4 v = *(const float4*)(src + k*4);
            r16[k*2  ] = pack2(v.x, v.y);
            r16[k*2+1] = pack2(v.z, v.w);
        }
        u32* dst = (u32*)xT + ((size_t)(b*4096 + hb*64 + s))*64 + kq*16;
#pragma unroll
        for (int k = 0; k < 4; ++k)
            *(uint4*)(dst + k*4) = *(uint4*)&r16[k*4];
    }
}

// ---- kernel 2: weight -> Wt bf16, A-fragment order (k = kpos*128+cin) --
__global__ __launch_bounds__(256) void k_wprep(const float* __restrict__ w,
                                               u16* __restrict__ Wt){
    int gid = blockIdx.x*256 + threadIdx.x;     // 0 .. 147455
    int jf   = gid & 7;
    int lane = (gid >> 3) & 63;
    int mt   = (gid >> 9) & 7;
    int kt   = gid >> 12;
    int m  = mt*16 + (lane & 15);
    int kk = (lane >> 4)*8 + jf;
    int ck = kt*32 + kk;
    int kpos = ck >> 7;
    int cin  = ck & 127;
    Wt[gid] = tobf(w[((size_t)m*128 + cin)*9 + kpos]);
}

// ---- kernel 3: deformable im2col (scatter stage, no barriers) ---------
// grid 9216 = 128 pos-blocks x 9 kpos x 8 b (b = bi&7 for XCD L2 locality).
// thread: cg = tid&7 (16-cin group), posl = tid>>3 (32 pos/block).
// 4 scattered 32B corner reads -> pk_fma blend -> coalesced 32B V store.
__global__ __launch_bounds__(256, 6)
void k_sample(const float* __restrict__ off, const u16* __restrict__ xT,
              u16* __restrict__ V){
    int tid = threadIdx.x, bi = blockIdx.x;
    int b  = bi & 7;
    int q  = bi >> 3;            // 0..1151
    int kpos = q % 9;
    int pb   = q / 9;            // 0..127
    int cg   = tid & 7;
    int pos  = pb*32 + (tid >> 3);
    int ho = pos >> 6, wo = pos & 63;

    // offsets (lanes with same pos broadcast; consecutive pos coalesce)
    size_t ob = ((size_t)(b*18 + 2*kpos))*4096 + pos;
    float dy = off[ob];
    float dx = off[ob + 4096];

    int kh = kpos / 3, kw = kpos - kh*3;
    float py = (float)(ho + kh - 1) + dy;
    float px = (float)(wo + kw - 1) + dx;
    float y0f = floorf(py), x0f = floorf(px);
    float ly = py - y0f, lx = px - x0f;
    int y0 = (int)y0f, x0 = (int)x0f;
    int y1 = y0 + 1,  x1 = x0 + 1;
    float my0 = (y0 >= 0 && y0 < Hh) ? 1.f : 0.f;
    float my1 = (y1 >= 0 && y1 < Hh) ? 1.f : 0.f;
    float mx0 = (x0 >= 0 && x0 < Ww) ? 1.f : 0.f;
    float mx1 = (x1 >= 0 && x1 < Ww) ? 1.f : 0.f;
    float oy = 1.f - ly, ox = 1.f - lx;
    float wt[4] = { oy*ox*my0*mx0, oy*lx*my0*mx1, ly*ox*my1*mx0, ly*lx*my1*mx1 };
    int cy0 = min(max(y0,0),Hh-1), cy1 = min(max(y1,0),Hh-1);
    int cx0 = min(max(x0,0),Ww-1), cx1 = min(max(x1,0),Ww-1);
    int aa[4] = { (cy0*Ww + cx0)*CIN, (cy0*Ww + cx1)*CIN,
                  (cy1*Ww + cx0)*CIN, (cy1*Ww + cx1)*CIN };

    const u16* xb = xT + (size_t)b*(Hh*Ww*CIN) + cg*16;
    uint4 g[4][2];
#pragma unroll
    for (int c = 0; c < 4; ++c){
        const u16* xc = xb + aa[c];
        g[c][0] = *(const uint4*)(xc);
        g[c][1] = *(const uint4*)(xc + 8);
    }

    u32 res[8];
#pragma unroll
    for (int d = 0; d < 8; ++d){
        f32x2 s2 = {0.f, 0.f};
#pragma unroll
        for (int c = 0; c < 4; ++c){
            u32 u = ((const u32*)&g[c][0])[d];
            f32x2 v  = { bflo(u), bfhi(u) };
            f32x2 w2 = { wt[c], wt[c] };
            s2 += w2 * v;                    // v_pk_fma_f32
        }
        res[d] = pack2(s2.x, s2.y);
    }

    u16* vp = V + ((((size_t)(b*8 + cg)*9 + kpos)*4096) + pos)*16;
    *(uint4*)(vp    ) = *(uint4*)&res[0];
    *(uint4*)(vp + 8) = *(uint4*)&res[4];
}

// ---- kernel 4: GEMM  C[128 cout x 64 pos] = Wt x V --------------------
// grid 512: b = bi&7, pt = bi>>3 (64-pos tile). 36 K-chunks of 32.
// B staged regs->padded LDS (conflict-free b-frags), depth-2 B prefetch,
// depth-1 A prefetch, dbuf LDS, one barrier per chunk.
__global__ __launch_bounds__(256, 2)
void k_gemm(const u16* __restrict__ V, const u16* __restrict__ Wt,
            const float* __restrict__ bias, float* __restrict__ out){
    // per buf: 2 slabs x 64 rows x 10 dw (40 B row: 32 data + 8 pad)
    __shared__ u32 Bsm[2][1280];

    int tid = threadIdx.x, bi = blockIdx.x;
    int b = bi & 7, pt = bi >> 3;           // pos tile 0..63
    int lane = tid & 63, wave = tid >> 6;
    int wm = wave >> 1, wn = wave & 1;
    int quad = lane >> 4, l16 = lane & 15;

    // staging identity: s = slab, row = pos-in-tile, half = 16B half
    int sS = tid >> 7, rowS = (tid >> 1) & 63, halfS = tid & 1;

    f32x4 acc[4][2];
#pragma unroll
    for (int i = 0; i < 4; ++i)
#pragma unroll
        for (int j = 0; j < 2; ++j) acc[i][j] = {0.f,0.f,0.f,0.f};

    auto loadB = [&](int kc, uint4& r){
        int kpos = kc >> 2, cg0 = (kc & 3)*2;
        const u16* vp = V + ((((size_t)(b*8 + cg0 + sS)*9 + kpos)*4096)
                             + pt*64 + rowS)*16 + halfS*8;
        r = *(const uint4*)vp;
    };
    auto storeB = [&](const uint4& r, int buf){
        *(uint4*)&Bsm[buf][sS*640 + rowS*10 + halfS*4] = r;
    };
    auto loadA = [&](int kc, uint4 a[4]){
        const u16* wp = Wt + (size_t)((kc*8 + wm*4)*64 + lane)*8;
#pragma unroll
        for (int i = 0; i < 4; ++i)
            a[i] = *(const uint4*)(wp + (size_t)i*64*8);
    };

    uint4 ringB[2], avC[4], avN[4];
    // prologue: chunk0 staged to Bsm[0]; chunk1 in ringB[1]; A(0),A(1) in regs
    loadB(0, ringB[0]);
    loadA(0, avC);
    storeB(ringB[0], 0);
    loadB(1, ringB[1]);
    loadA(1, avN);
    __syncthreads();                        // Bsm[0] ready

    for (int kc = 0; kc < NCHUNK; ++kc){
        int c1 = kc + 1, c2 = kc + 2;
        if (c2 < NCHUNK) loadB(c2, ringB[kc & 1]);   // ringB[kc&1] already consumed

        // b-frags for chunk kc from Bsm[kc&1]
        uint4 braw[2];
#pragma unroll
        for (int j = 0; j < 2; ++j){
            int n = wn*32 + j*16 + l16;
            braw[j] = *(const uint4*)&Bsm[kc & 1][(quad >> 1)*640 + n*10 + (quad & 1)*4];
        }
#pragma unroll
        for (int i = 0; i < 4; ++i){
            bf16x8 a = __builtin_bit_cast(bf16x8, avC[i]);
#pragma unroll
            for (int j = 0; j < 2; ++j){
                bf16x8 bv = __builtin_bit_cast(bf16x8, braw[j]);
                acc[i][j] = __builtin_amdgcn_mfma_f32_16x16x32_bf16(a, bv, acc[i][j], 0, 0, 0);
            }
        }

        if (c1 < NCHUNK){
            storeB(ringB[c1 & 1], c1 & 1);          // chunk kc+1 -> Bsm[(kc+1)&1]
#pragma unroll
            for (int i = 0; i < 4; ++i) avC[i] = avN[i];
            if (c2 < NCHUNK) loadA(c2, avN);
        }
        __syncthreads();
    }

    // epilogue: D[row=quad*4+r][col=l16] + bias
#pragma unroll
    for (int i = 0; i < 4; ++i){
        int cout0 = (wm*4 + i)*16 + quad*4;
#pragma unroll
        for (int j = 0; j < 2; ++j){
            int pcol = wn*32 + j*16 + l16;
            size_t obase = ((size_t)(b*COUT + cout0))*4096 + pt*64 + pcol;
#pragma unroll
            for (int r = 0; r < 4; ++r)
                out[obase + (size_t)r*4096] = acc[i][j][r] + bias[cout0 + r];
        }
    }
}

// ---- launch -----------------------------------------------------------
extern "C" void kernel_launch(void* const* d_in, const int* in_sizes, int n_in,
                              void* d_out, int out_size, void* d_ws, size_t ws_size,
                              hipStream_t stream){
    const float* x    = (const float*)d_in[0];
    const float* off  = (const float*)d_in[1];
    const float* w    = (const float*)d_in[2];
    const float* bias = (const float*)d_in[3];
    float* out = (float*)d_out;

    u16* xT = (u16*)d_ws;                    // 8 MB
    u16* Wt = xT + XT_ELEMS;                 // 288 KB
    u16* V  = Wt + WT_ELEMS;                 // 75.5 MB

    k_transpose<<<dim3(512),  dim3(256), 0, stream>>>(x, xT);
    k_wprep    <<<dim3(576),  dim3(256), 0, stream>>>(w, Wt);
    k_sample   <<<dim3(9216), dim3(256), 0, stream>>>(off, xT, V);
    k_gemm     <<<dim3(512),  dim3(256), 0, stream>>>(V, Wt, bias, out);
}